// Round 6
// baseline (452.880 us; speedup 1.0000x reference)
//
#include <hip/hip_runtime.h>
#include <hip/hip_bf16.h>
#include <hip/hip_cooperative_groups.h>

namespace cg = cooperative_groups;

// MANN fused v4b: ONE cooperative launch (+ non-coop 4-launch fallback).
// B=512, IN=480, OUT=400, HID=512, K=8.
// Theory: previous 4-launch version (133us) was ~10x over roofline (~15us of
// real work) due to 3 inter-kernel gaps/drain tails + 1 block/CU (1 wave/SIMD,
// every vmcnt(0)+barrier drain exposed) + W-cvt serialized ahead of all MFMA.
// v4: grid 512 x 256 cooperative, grid.sync() between phases.
//  phase0: gating MLP (1 row/block) + x->bf16 + W1 cvt
//  phase1: layer1 (m-tile 32, o-tile 16) + W2 cvt overlapped
//  phase2: layer2 + W3 cvt overlapped
//  phase3: layer3 (fp32 out)
// Layer tiling: KW=64 windows double-buffered (2x16KB = 32KB LDS -> 2 blocks/CU
// co-resident, required for cooperative validation). Wave = 2 m-subtiles x 2
// experts: each ds_read_b128 B-frag feeds 2 MFMAs. Staging via
// global_load_lds width=16, linear LDS dest; XOR swizzle on the GLOBAL side:
// LDS slot (r,slot) holds global chunk c = slot ^ (r&7) so ds_read_b128 hits
// the structural b128 floor only. Epilogue: 4-plane expert blend via LDS.
// v4b adds: kernel_launch checks the coop-launch return code; on error it
// falls back to 4 plain launches of the same device code (2 blocks/CU tiling
// + cvt overlap preserved). Rounds 1-5 were GPUAcquisitionTimeouts.

typedef __hip_bfloat16 bf16;
typedef unsigned short u16;
typedef __attribute__((ext_vector_type(8))) short bf16x8;
typedef __attribute__((ext_vector_type(4))) float f32x4;

__device__ __forceinline__ float elu1(float x) { return x > 0.f ? x : expm1f(x); }

__device__ __forceinline__ u16 cvt1(float v) {
    union { bf16 h; u16 u; } c;
    c.h = __float2bfloat16(v);          // RNE
    return c.u;
}

__device__ __forceinline__ void async16(const u16* g, u16* l) {
    __builtin_amdgcn_global_load_lds(
        (const __attribute__((address_space(1))) void*)g,
        (__attribute__((address_space(3))) void*)l, 16, 0, 0);
}

// fp32 -> bf16, NU 8-elem units per block (block b owns units [b*NU, (b+1)*NU))
template <int NU>
__device__ __forceinline__ void cvt_units(const float* __restrict__ src,
                                          u16* __restrict__ dst, int b, int tid)
{
    #pragma unroll
    for (int jj = 0; jj < (NU + 255) / 256; ++jj) {
        const int local = jj * 256 + tid;
        if ((NU & 255) && local >= NU) break;
        const size_t off = ((size_t)b * NU + local) * 8;
        float4 a = *(const float4*)(src + off);
        float4 c = *(const float4*)(src + off + 4);
        union { u16 h[8]; uint4 v; } o;
        o.h[0] = cvt1(a.x); o.h[1] = cvt1(a.y); o.h[2] = cvt1(a.z); o.h[3] = cvt1(a.w);
        o.h[4] = cvt1(c.x); o.h[5] = cvt1(c.y); o.h[6] = cvt1(c.z); o.h[7] = cvt1(c.w);
        *(uint4*)(dst + off) = o.v;
    }
}

// ---------------- phase 0 body: gating MLP + x-cvt + W1-cvt ----------------
__device__ __forceinline__ void phase0_body(
    const float* __restrict__ x, const int* __restrict__ idx_raw,
    const float* __restrict__ GW1, const float* __restrict__ Gb1,
    const float* __restrict__ GW2, const float* __restrict__ Gb2,
    const float* __restrict__ GW3, const float* __restrict__ Gb3,
    const float* __restrict__ Wk1,
    float* __restrict__ gout, u16* __restrict__ xbf, u16* __restrict__ Wb1,
    u16* wbuf, int b, int j)
{
    float* xg = (float*)wbuf;                // 32
    float* h1 = xg + 32;                     // 128
    float* h2 = h1 + 128;                    // 128

    if (j < 32) {
        // gating_idx may arrive as int32 or int64; word1==0 iff int64
        int ii;
        if (idx_raw[1] == 0) ii = (int)((const long long*)idx_raw)[j];
        else                 ii = idx_raw[j];
        if (ii < 0 || ii >= 480) ii = 448 + j;  // memory-safety clamp
        xg[j] = x[(size_t)b * 480 + ii];
    }
    __syncthreads();

    if (j < 128) {
        float a = Gb1[j];
        #pragma unroll
        for (int i = 0; i < 32; ++i) a += xg[i] * GW1[i * 128 + j];
        h1[j] = elu1(a);
    }
    __syncthreads();

    if (j < 128) {
        float a2 = Gb2[j];
        #pragma unroll 8
        for (int i = 0; i < 128; ++i) a2 += h1[i] * GW2[i * 128 + j];
        h2[j] = elu1(a2);
    }
    __syncthreads();

    if (j < 8) {
        float a3 = Gb3[j];
        for (int i = 0; i < 128; ++i) a3 += h2[i] * GW3[i * 8 + j];
        gout[b * 8 + j] = a3;                // no activation on blend coeffs
    }

    // x -> bf16 (this block's row)
    for (int i = j; i < 480; i += 256)
        xbf[b * 480 + i] = cvt1(x[b * 480 + i]);

    // W1 -> bf16: 245760 units / 512 blocks = 480 units/block
    cvt_units<480>(Wk1, Wb1, b, j);
}

// out[b,o] = act( sum_k g[b,k] * ( sum_i A[b,i]*Wk[k,o,i] + bk[k,o] ) )
// block: o-tile 16 (bid&31) x m-tile 32 (bid>>5). Note: all 16 m-tiles of one
// o-tile land on the same XCD (bid = ot + 32m -> bid%8 = ot%8) -> W-tile is
// read 16x from one XCD's L2.
template <int IDIM, int ODIM, bool ELU, typename OutT>
__device__ __forceinline__ void layer_phase(
    const u16* __restrict__ A,     // [512, IDIM] bf16
    const u16* __restrict__ Wb,    // [8, ODIM, IDIM] bf16
    const float* __restrict__ bk,  // [8, ODIM] fp32
    const float* __restrict__ gv,  // [512, 8] fp32
    OutT* __restrict__ out,        // [512, ODIM]
    u16* wbuf)                     // [2][128*64] u16 (32 KB)
{
    constexpr int KW = 64;                       // K-window (halfwords)
    constexpr int NW = (IDIM + KW - 1) / KW;     // 8 windows
    const int bid = blockIdx.x;
    const int o0 = (bid & 31) * 16;
    if (o0 >= ODIM) return;                      // ODIM=400: 7 o-tiles idle (uniform per block)
    const int m0  = (bid >> 5) * 32;
    const int tid = threadIdx.x;
    const int wid = tid >> 6, lane = tid & 63;
    const int n = lane & 15, quad = lane >> 4;
    const int e0 = wid * 2;                      // wave expert-pair

    // 16 KB/window = 4 global_load_lds per wave. instr t fills 16B-slots
    // L = (wid*4+t)*64 + lane; r = L>>3 (= e*16+nr), slot = L&7; slot holds
    // global chunk c = slot ^ (nr&7).
    auto stage = [&](int w, u16* buf) {
        const int w0 = w * KW;
        #pragma unroll
        for (int t = 0; t < 4; ++t) {
            const int L = (wid * 4 + t) * 64 + lane;
            const int r = L >> 3, slot = L & 7;
            const int e = r >> 4, nr = r & 15;
            int koff = w0 + (slot ^ (nr & 7)) * 8;
            if (koff + 8 > IDIM) koff = IDIM - 8;   // clamp; never read
            async16(Wb + ((size_t)(e * ODIM + o0 + nr)) * IDIM + koff,
                    buf + (size_t)(wid * 4 + t) * 512);
        }
    };

    const f32x4 zero = {0.f, 0.f, 0.f, 0.f};
    f32x4 acc[2][2] = {{zero, zero}, {zero, zero}};

    stage(0, wbuf);
    __syncthreads();                 // barrier implies vmcnt(0) drain

    for (int w = 0; w < NW; ++w) {
        if (w + 1 < NW) stage(w + 1, wbuf + ((w + 1) & 1) * (128 * KW));
        const u16* buf = wbuf + (w & 1) * (128 * KW);
        #pragma unroll
        for (int cl = 0; cl < KW / 32; ++cl) {
            const int i0 = w * KW + cl * 32;
            if (i0 >= IDIM) break;               // trims last window (IDIM=480)
            bf16x8 af[2];
            #pragma unroll
            for (int s = 0; s < 2; ++s)
                af[s] = *(const bf16x8*)(A + (size_t)(m0 + 16 * s + n) * IDIM
                                           + i0 + quad * 8);
            const int cw = cl * 4 + quad;        // chunk 0..7 within window
            const int sl = (cw ^ (n & 7)) * 8;
            #pragma unroll
            for (int jj = 0; jj < 2; ++jj) {
                bf16x8 bfr = *(const bf16x8*)(buf + ((e0 + jj) * 16 + n) * KW + sl);
                acc[0][jj] = __builtin_amdgcn_mfma_f32_16x16x32_bf16(af[0], bfr, acc[0][jj], 0, 0, 0);
                acc[1][jj] = __builtin_amdgcn_mfma_f32_16x16x32_bf16(af[1], bfr, acc[1][jj], 0, 0, 0);
            }
        }
        __syncthreads();             // drains stage(w+1) + protects reuse
    }

    // ---- epilogue: each wave blends its 2 experts; 4 planes summed via LDS.
    // C/D layout: col = lane&15 (=n), row = quad*4 + reg (batch).
    float* part = (float*)wbuf;      // [4][32][17] fp32, 8.7 KB
    float bkv[2];
    #pragma unroll
    for (int jj = 0; jj < 2; ++jj) bkv[jj] = bk[(e0 + jj) * ODIM + o0 + n];

    #pragma unroll
    for (int s = 0; s < 2; ++s) {
        #pragma unroll
        for (int r = 0; r < 4; ++r) {
            const int lrow = 16 * s + 4 * quad + r;
            const int grow = m0 + lrow;
            float v = 0.f;
            #pragma unroll
            for (int jj = 0; jj < 2; ++jj)
                v += gv[grow * 8 + e0 + jj] * (acc[s][jj][r] + bkv[jj]);
            part[(wid * 32 + lrow) * 17 + n] = v;
        }
    }
    __syncthreads();

    #pragma unroll
    for (int rr = 0; rr < 2; ++rr) {
        const int lrow = rr * 16 + (tid >> 4);
        const int col  = tid & 15;
        float v = part[lrow * 17 + col] + part[(32 + lrow) * 17 + col]
                + part[(64 + lrow) * 17 + col] + part[(96 + lrow) * 17 + col];
        if (ELU) v = elu1(v);
        if constexpr (__hip_internal::is_same<OutT, float>::value)
            out[(size_t)(m0 + lrow) * ODIM + o0 + col] = v;
        else
            out[(size_t)(m0 + lrow) * ODIM + o0 + col] = cvt1(v);
    }
}

// ---------------- primary: single cooperative kernel ----------------
__global__ __launch_bounds__(256, 2) void fused_mann(
    const float* __restrict__ x, const int* __restrict__ idx_raw,
    const float* __restrict__ GW1, const float* __restrict__ Gb1,
    const float* __restrict__ GW2, const float* __restrict__ Gb2,
    const float* __restrict__ GW3, const float* __restrict__ Gb3,
    const float* __restrict__ Wk1, const float* __restrict__ bk1,
    const float* __restrict__ Wk2, const float* __restrict__ bk2,
    const float* __restrict__ Wk3, const float* __restrict__ bk3,
    float* __restrict__ gout, u16* __restrict__ xbf,
    u16* __restrict__ A1, u16* __restrict__ A2,
    u16* __restrict__ Wb1, u16* __restrict__ Wb2, u16* __restrict__ Wb3,
    float* __restrict__ outp)
{
    __shared__ u16 wbuf[2][128 * 64];            // 32 KB -> 2 blocks/CU
    cg::grid_group gg = cg::this_grid();
    const int b = blockIdx.x;                    // 512 blocks = 512 batch rows
    const int j = threadIdx.x;

    phase0_body(x, idx_raw, GW1, Gb1, GW2, Gb2, GW3, Gb3, Wk1,
                gout, xbf, Wb1, &wbuf[0][0], b, j);
    __threadfence();
    gg.sync();

    layer_phase<480, 512, true, u16>(xbf, Wb1, bk1, gout, A1, &wbuf[0][0]);
    cvt_units<512>(Wk2, Wb2, b, j);              // 262144/512 = 512 units/block
    __threadfence();
    gg.sync();

    layer_phase<512, 512, true, u16>(A1, Wb2, bk2, gout, A2, &wbuf[0][0]);
    cvt_units<400>(Wk3, Wb3, b, j);              // 204800/512 = 400 units/block
    __threadfence();
    gg.sync();

    layer_phase<512, 400, false, float>(A2, Wb3, bk3, gout, outp, &wbuf[0][0]);
}

// ---------------- fallback: 4 plain launches, same device code ----------------
__global__ __launch_bounds__(256, 2) void k_phase0(
    const float* __restrict__ x, const int* __restrict__ idx_raw,
    const float* __restrict__ GW1, const float* __restrict__ Gb1,
    const float* __restrict__ GW2, const float* __restrict__ Gb2,
    const float* __restrict__ GW3, const float* __restrict__ Gb3,
    const float* __restrict__ Wk1,
    float* __restrict__ gout, u16* __restrict__ xbf, u16* __restrict__ Wb1)
{
    __shared__ u16 wbuf[2][128 * 64];
    phase0_body(x, idx_raw, GW1, Gb1, GW2, Gb2, GW3, Gb3, Wk1,
                gout, xbf, Wb1, &wbuf[0][0], blockIdx.x, threadIdx.x);
}

template <int IDIM, int ODIM, bool ELU, typename OutT, int NU_NEXT>
__global__ __launch_bounds__(256, 2) void k_layer(
    const u16* __restrict__ A, const u16* __restrict__ Wb,
    const float* __restrict__ bk, const float* __restrict__ gv,
    OutT* __restrict__ out,
    const float* __restrict__ Wnext_src, u16* __restrict__ Wnext_dst)
{
    __shared__ u16 wbuf[2][128 * 64];
    layer_phase<IDIM, ODIM, ELU, OutT>(A, Wb, bk, gv, out, &wbuf[0][0]);
    if constexpr (NU_NEXT > 0)
        cvt_units<NU_NEXT>(Wnext_src, Wnext_dst, blockIdx.x, threadIdx.x);
}

extern "C" void kernel_launch(void* const* d_in, const int* in_sizes, int n_in,
                              void* d_out, int out_size, void* d_ws, size_t ws_size,
                              hipStream_t stream)
{
    const float* x   = (const float*)d_in[0];
    const int* gidx  = (const int*)d_in[1];
    const float* GW1 = (const float*)d_in[2];
    const float* Gb1 = (const float*)d_in[3];
    const float* GW2 = (const float*)d_in[4];
    const float* Gb2 = (const float*)d_in[5];
    const float* GW3 = (const float*)d_in[6];
    const float* Gb3 = (const float*)d_in[7];
    const float* Wk1 = (const float*)d_in[8];
    const float* bk1 = (const float*)d_in[9];
    const float* Wk2 = (const float*)d_in[10];
    const float* bk2 = (const float*)d_in[11];
    const float* Wk3 = (const float*)d_in[12];
    const float* bk3 = (const float*)d_in[13];

    char* ws  = (char*)d_ws;
    float* g  = (float*)ws;                          // @0      (16 KB)
    u16* xbf  = (u16*)(ws + (64 << 10));             // @64 KB  (480 KB)
    u16* A1   = (u16*)(ws + (1 << 20));              // @1 MB   (512 KB)
    u16* A2   = (u16*)(ws + (1 << 20) + (512 << 10));// @1.5 MB (512 KB)
    u16* Wb1  = (u16*)(ws + (2 << 20));              // @2 MB   (3.75 MB)
    u16* Wb2  = (u16*)(ws + (6 << 20));              // @6 MB   (4 MB exact)
    u16* Wb3  = (u16*)(ws + (10 << 20));             // @10 MB  (3.13 MB)
    float* outp = (float*)d_out;

    void* params[] = {
        (void*)&x,   (void*)&gidx, (void*)&GW1, (void*)&Gb1,
        (void*)&GW2, (void*)&Gb2,  (void*)&GW3, (void*)&Gb3,
        (void*)&Wk1, (void*)&bk1,  (void*)&Wk2, (void*)&bk2,
        (void*)&Wk3, (void*)&bk3,
        (void*)&g,   (void*)&xbf,  (void*)&A1,  (void*)&A2,
        (void*)&Wb1, (void*)&Wb2,  (void*)&Wb3, (void*)&outp
    };
    hipError_t err = hipLaunchCooperativeKernel(fused_mann, dim3(512), dim3(256),
                                                params, 0u, stream);
    if (err != hipSuccess) {
        // fallback: same device code as 4 ordinary launches (kernel-boundary
        // ordering replaces grid.sync; cvt overlap kept inside layer kernels)
        k_phase0<<<512, 256, 0, stream>>>(x, gidx, GW1, Gb1, GW2, Gb2,
                                          GW3, Gb3, Wk1, g, xbf, Wb1);
        k_layer<480, 512, true,  u16,  512><<<512, 256, 0, stream>>>(
            xbf, Wb1, bk1, g, A1, Wk2, Wb2);
        k_layer<512, 512, true,  u16,  400><<<512, 256, 0, stream>>>(
            A1,  Wb2, bk2, g, A2, Wk3, Wb3);
        k_layer<512, 400, false, float, 0><<<512, 256, 0, stream>>>(
            A2,  Wb3, bk3, g, (float*)d_out, (const float*)nullptr, (u16*)nullptr);
    }
    (void)outp;
}

// Round 7
// 139.761 us; speedup vs baseline: 3.2404x; 3.2404x over previous
//
#include <hip/hip_runtime.h>
#include <hip/hip_bf16.h>

// MANN fused v5: 4 plain launches (grid-sync via kernel boundary).
// B=512, IN=480, OUT=400, HID=512, K=8.
// Round-6 evidence: cooperative single-launch ran at 350us with VALUBusy
// 0.97% / MfmaUtil 0.65% / 1.4% HBM -- ~97% of the time all waves idle in
// grid.sync() spin + device-scope release/acquire (~110us per sync on 8
// non-coherent XCD L2s). Kernel boundaries are the cheap grid barrier here.
// Traffic plan validated by r6 counters: FETCH 23.9MB / WRITE 13.5MB = ideal.
// v5 keeps: 512-block layer grid (2 blocks/CU, 8 waves/CU TLP), KW=64
// double-buffered LDS W-staging via global_load_lds w16 (global-side XOR
// swizzle), W2/W3 fp32->bf16 cvt folded into layer1/layer2 kernels.
// v5 adds: A preloaded into registers ONCE per layer kernel (15-16 bf16x8
// per m-subtile per lane, ~120-128 VGPR, fully unrolled static indexing) --
// removes the per-cl global A load latency that 2 waves/SIMD cannot hide.

typedef __hip_bfloat16 bf16;
typedef unsigned short u16;
typedef __attribute__((ext_vector_type(8))) short bf16x8;
typedef __attribute__((ext_vector_type(4))) float f32x4;

__device__ __forceinline__ float elu1(float x) { return x > 0.f ? x : expm1f(x); }

__device__ __forceinline__ u16 cvt1(float v) {
    union { bf16 h; u16 u; } c;
    c.h = __float2bfloat16(v);          // RNE
    return c.u;
}

__device__ __forceinline__ void async16(const u16* g, u16* l) {
    __builtin_amdgcn_global_load_lds(
        (const __attribute__((address_space(1))) void*)g,
        (__attribute__((address_space(3))) void*)l, 16, 0, 0);
}

// fp32 -> bf16, NU 8-elem units per block (block b owns units [b*NU, (b+1)*NU))
template <int NU>
__device__ __forceinline__ void cvt_units(const float* __restrict__ src,
                                          u16* __restrict__ dst, int b, int tid)
{
    #pragma unroll
    for (int jj = 0; jj < (NU + 255) / 256; ++jj) {
        const int local = jj * 256 + tid;
        if ((NU & 255) && local >= NU) break;
        const size_t off = ((size_t)b * NU + local) * 8;
        float4 a = *(const float4*)(src + off);
        float4 c = *(const float4*)(src + off + 4);
        union { u16 h[8]; uint4 v; } o;
        o.h[0] = cvt1(a.x); o.h[1] = cvt1(a.y); o.h[2] = cvt1(a.z); o.h[3] = cvt1(a.w);
        o.h[4] = cvt1(c.x); o.h[5] = cvt1(c.y); o.h[6] = cvt1(c.z); o.h[7] = cvt1(c.w);
        *(uint4*)(dst + off) = o.v;
    }
}

// ---------------- kernel 1: gating MLP + x-cvt + W1-cvt ----------------
__global__ __launch_bounds__(256) void k_phase0(
    const float* __restrict__ x, const int* __restrict__ idx_raw,
    const float* __restrict__ GW1, const float* __restrict__ Gb1,
    const float* __restrict__ GW2, const float* __restrict__ Gb2,
    const float* __restrict__ GW3, const float* __restrict__ Gb3,
    const float* __restrict__ Wk1,
    float* __restrict__ gout, u16* __restrict__ xbf, u16* __restrict__ Wb1)
{
    __shared__ float xg[32];
    __shared__ float h1[128];
    __shared__ float h2[128];
    const int b = blockIdx.x;
    const int j = threadIdx.x;

    if (j < 32) {
        // gating_idx may arrive as int32 or int64; word1==0 iff int64
        int ii;
        if (idx_raw[1] == 0) ii = (int)((const long long*)idx_raw)[j];
        else                 ii = idx_raw[j];
        if (ii < 0 || ii >= 480) ii = 448 + j;  // memory-safety clamp
        xg[j] = x[(size_t)b * 480 + ii];
    }
    __syncthreads();

    if (j < 128) {
        float a = Gb1[j];
        #pragma unroll
        for (int i = 0; i < 32; ++i) a += xg[i] * GW1[i * 128 + j];
        h1[j] = elu1(a);
    }
    __syncthreads();

    if (j < 128) {
        float a2 = Gb2[j];
        #pragma unroll 8
        for (int i = 0; i < 128; ++i) a2 += h1[i] * GW2[i * 128 + j];
        h2[j] = elu1(a2);
    }
    __syncthreads();

    if (j < 8) {
        float a3 = Gb3[j];
        for (int i = 0; i < 128; ++i) a3 += h2[i] * GW3[i * 8 + j];
        gout[b * 8 + j] = a3;                // no activation on blend coeffs
    }

    // x -> bf16 (this block's row)
    for (int i = j; i < 480; i += 256)
        xbf[b * 480 + i] = cvt1(x[b * 480 + i]);

    // W1 -> bf16: 245760 units / 512 blocks = 480 units/block
    cvt_units<480>(Wk1, Wb1, b, j);
}

// out[b,o] = act( sum_k g[b,k] * ( sum_i A[b,i]*Wk[k,o,i] + bk[k,o] ) )
// block: o-tile 16 (bid&31) x m-tile 32 (bid>>5). All 16 m-tiles of one
// o-tile land on the same XCD (bid%8 = ot%8) -> W-tile L2-local, read 16x.
template <int IDIM, int ODIM, bool ELU, typename OutT>
__device__ __forceinline__ void layer_phase(
    const u16* __restrict__ A,     // [512, IDIM] bf16
    const u16* __restrict__ Wb,    // [8, ODIM, IDIM] bf16
    const float* __restrict__ bk,  // [8, ODIM] fp32
    const float* __restrict__ gv,  // [512, 8] fp32
    OutT* __restrict__ out,        // [512, ODIM]
    u16* wbuf)                     // [2][128*64] u16 (32 KB)
{
    constexpr int KW = 64;                       // K-window (halfwords)
    constexpr int NW = (IDIM + KW - 1) / KW;     // 8 windows
    constexpr int NC = IDIM / 32;                // 15 (480) or 16 (512) chunks
    const int bid = blockIdx.x;
    const int o0 = (bid & 31) * 16;
    if (o0 >= ODIM) return;                      // ODIM=400: uniform per block
    const int m0  = (bid >> 5) * 32;
    const int tid = threadIdx.x;
    const int wid = tid >> 6, lane = tid & 63;
    const int n = lane & 15, quad = lane >> 4;
    const int e0 = wid * 2;                      // wave expert-pair

    // ---- A preload: whole wave A-slice to registers (static indices only;
    // rule: runtime-indexed ext_vector arrays spill to scratch). 16B loads,
    // fully pipelined; ~120-128 VGPR. Removes per-window global latency.
    bf16x8 areg[2][NC];
    #pragma unroll
    for (int s = 0; s < 2; ++s)
        #pragma unroll
        for (int c = 0; c < NC; ++c)
            areg[s][c] = *(const bf16x8*)(A + (size_t)(m0 + 16 * s + n) * IDIM
                                            + c * 32 + quad * 8);

    // 16 KB/window = 4 global_load_lds per wave. instr t fills 16B-slots
    // L = (wid*4+t)*64 + lane; r = L>>3 (= e*16+nr), slot = L&7; slot holds
    // global chunk c = slot ^ (nr&7)  (global-side XOR swizzle).
    auto stage = [&](int w, u16* buf) {
        const int w0 = w * KW;
        #pragma unroll
        for (int t = 0; t < 4; ++t) {
            const int L = (wid * 4 + t) * 64 + lane;
            const int r = L >> 3, slot = L & 7;
            const int e = r >> 4, nr = r & 15;
            int koff = w0 + (slot ^ (nr & 7)) * 8;
            if (koff + 8 > IDIM) koff = IDIM - 8;   // clamp; never read
            async16(Wb + ((size_t)(e * ODIM + o0 + nr)) * IDIM + koff,
                    buf + (size_t)(wid * 4 + t) * 512);
        }
    };

    const f32x4 zero = {0.f, 0.f, 0.f, 0.f};
    f32x4 acc[2][2] = {{zero, zero}, {zero, zero}};

    stage(0, wbuf);
    __syncthreads();                 // barrier implies vmcnt(0) drain

    #pragma unroll
    for (int w = 0; w < NW; ++w) {
        if (w + 1 < NW) stage(w + 1, wbuf + ((w + 1) & 1) * (128 * KW));
        const u16* buf = wbuf + (w & 1) * (128 * KW);
        #pragma unroll
        for (int cl = 0; cl < 2; ++cl) {
            const int c = w * 2 + cl;
            if (c >= NC) break;                  // static after unroll
            const int cw = cl * 4 + quad;        // chunk 0..7 within window
            const int sl = (cw ^ (n & 7)) * 8;
            #pragma unroll
            for (int jj = 0; jj < 2; ++jj) {
                bf16x8 bfr = *(const bf16x8*)(buf + ((e0 + jj) * 16 + n) * KW + sl);
                acc[0][jj] = __builtin_amdgcn_mfma_f32_16x16x32_bf16(areg[0][c], bfr, acc[0][jj], 0, 0, 0);
                acc[1][jj] = __builtin_amdgcn_mfma_f32_16x16x32_bf16(areg[1][c], bfr, acc[1][jj], 0, 0, 0);
            }
        }
        __syncthreads();             // drains stage(w+1) + protects reuse
    }

    // ---- epilogue: each wave blends its 2 experts; 4 planes summed via LDS.
    // C/D layout: col = lane&15 (=n), row = quad*4 + reg (batch).
    float* part = (float*)wbuf;      // [4][32][17] fp32, 8.7 KB
    float bkv[2];
    #pragma unroll
    for (int jj = 0; jj < 2; ++jj) bkv[jj] = bk[(e0 + jj) * ODIM + o0 + n];

    #pragma unroll
    for (int s = 0; s < 2; ++s) {
        #pragma unroll
        for (int r = 0; r < 4; ++r) {
            const int lrow = 16 * s + 4 * quad + r;
            const int grow = m0 + lrow;
            float v = 0.f;
            #pragma unroll
            for (int jj = 0; jj < 2; ++jj)
                v += gv[grow * 8 + e0 + jj] * (acc[s][jj][r] + bkv[jj]);
            part[(wid * 32 + lrow) * 17 + n] = v;
        }
    }
    __syncthreads();

    #pragma unroll
    for (int rr = 0; rr < 2; ++rr) {
        const int lrow = rr * 16 + (tid >> 4);
        const int col  = tid & 15;
        float v = part[lrow * 17 + col] + part[(32 + lrow) * 17 + col]
                + part[(64 + lrow) * 17 + col] + part[(96 + lrow) * 17 + col];
        if (ELU) v = elu1(v);
        if constexpr (__hip_internal::is_same<OutT, float>::value)
            out[(size_t)(m0 + lrow) * ODIM + o0 + col] = v;
        else
            out[(size_t)(m0 + lrow) * ODIM + o0 + col] = cvt1(v);
    }
}

// kernels 2-4: layer (+ next-W cvt overlap where applicable)
template <int IDIM, int ODIM, bool ELU, typename OutT, int NU_NEXT>
__global__ __launch_bounds__(256, 2) void k_layer(
    const u16* __restrict__ A, const u16* __restrict__ Wb,
    const float* __restrict__ bk, const float* __restrict__ gv,
    OutT* __restrict__ out,
    const float* __restrict__ Wnext_src, u16* __restrict__ Wnext_dst)
{
    __shared__ u16 wbuf[2][128 * 64];            // 32 KB -> 2 blocks/CU
    layer_phase<IDIM, ODIM, ELU, OutT>(A, Wb, bk, gv, out, &wbuf[0][0]);
    if constexpr (NU_NEXT > 0)
        cvt_units<NU_NEXT>(Wnext_src, Wnext_dst, blockIdx.x, threadIdx.x);
}

extern "C" void kernel_launch(void* const* d_in, const int* in_sizes, int n_in,
                              void* d_out, int out_size, void* d_ws, size_t ws_size,
                              hipStream_t stream)
{
    const float* x   = (const float*)d_in[0];
    const int* gidx  = (const int*)d_in[1];
    const float* GW1 = (const float*)d_in[2];
    const float* Gb1 = (const float*)d_in[3];
    const float* GW2 = (const float*)d_in[4];
    const float* Gb2 = (const float*)d_in[5];
    const float* GW3 = (const float*)d_in[6];
    const float* Gb3 = (const float*)d_in[7];
    const float* Wk1 = (const float*)d_in[8];
    const float* bk1 = (const float*)d_in[9];
    const float* Wk2 = (const float*)d_in[10];
    const float* bk2 = (const float*)d_in[11];
    const float* Wk3 = (const float*)d_in[12];
    const float* bk3 = (const float*)d_in[13];

    char* ws  = (char*)d_ws;
    float* g  = (float*)ws;                          // @0      (16 KB)
    u16* xbf  = (u16*)(ws + (64 << 10));             // @64 KB  (480 KB)
    u16* A1   = (u16*)(ws + (1 << 20));              // @1 MB   (512 KB)
    u16* A2   = (u16*)(ws + (1 << 20) + (512 << 10));// @1.5 MB (512 KB)
    u16* Wb1  = (u16*)(ws + (2 << 20));              // @2 MB   (3.75 MB)
    u16* Wb2  = (u16*)(ws + (6 << 20));              // @6 MB   (4 MB exact)
    u16* Wb3  = (u16*)(ws + (10 << 20));             // @10 MB  (3.13 MB)

    k_phase0<<<512, 256, 0, stream>>>(x, gidx, GW1, Gb1, GW2, Gb2,
                                      GW3, Gb3, Wk1, g, xbf, Wb1);
    k_layer<480, 512, true,  u16,  512><<<512, 256, 0, stream>>>(
        xbf, Wb1, bk1, g, A1, Wk2, Wb2);
    k_layer<512, 512, true,  u16,  400><<<512, 256, 0, stream>>>(
        A1,  Wb2, bk2, g, A2, Wk3, Wb3);
    k_layer<512, 400, false, float, 0><<<512, 256, 0, stream>>>(
        A2,  Wb3, bk3, g, (float*)d_out, (const float*)nullptr, (u16*)nullptr);
}